// Round 5
// baseline (125.372 us; speedup 1.0000x reference)
//
#include <hip/hip_runtime.h>

// Reference-exact fp32 d2: no FMA contraction. d2 = (sqn+sqm) + dot' with
// dot' built from (-2x) pre-scaled m-points is bit-identical to the ref's
// (sqn+sqm) - 2*dot (power-of-2 scaling / negation commute with rounding).
// Self-distance: dt(n,n) = -2*sq_n exactly, so d2(n,n) == 0 exactly.
#pragma clang fp contract(off)

#define NBATCH 256   // B*L
#define NPTS   512   // points per batch
#define JDIM   128   // logit dim
#define NPAIR  (NBATCH * NPTS)   // 131072

// ---------------- K1: merge-free per-point argmax / masked-argmin -----------
// 1024 blocks x 128 threads (quarter-batch per block, 8 KB LDS) -> ~10
// blocks/CU resident, no barriers after staging, no cross-thread merge.
// Thread t owns point p = q*128+t and scans ALL 512 m ascending with strict
// compares (bmax seeds at -1; min candidates require d2>0, folding the ref's
// clamp(d2)==0 self/dupe mask into the compare) -> first-occurrence indices
// identical to the verified round-0/2/4 logic, indices stay in registers.
__global__ __launch_bounds__(128) void argmm_kernel(
    const float* __restrict__ xyz,   // [NBATCH, NPTS, 3]
    int* __restrict__ pmax,          // [NBATCH*NPTS]
    int* __restrict__ pmin)          // [NBATCH*NPTS]
{
    __shared__ float4 xyzS[NPTS];            // scaled (-2x,-2y,-2z, sq): 8 KB

    const int t  = threadIdx.x;              // 0..127
    const int bl = blockIdx.x >> 2;          // batch
    const int qq = blockIdx.x & 3;           // point-quarter of this block
    const float* xp = xyz + (size_t)bl * NPTS * 3;

    // stage all 512 points, scaled; sq computed in ref order from raw values
    #pragma unroll
    for (int i = 0; i < 4; ++i) {
        int m = t + i * 128;
        float x = xp[3 * m], y = xp[3 * m + 1], z = xp[3 * m + 2];
        float sq = (x * x + y * y) + z * z;  // matches np.sum(x*x,-1)
        xyzS[m] = make_float4(-2.0f * x, -2.0f * y, -2.0f * z, sq);
    }

    // own point raw from global
    const int p = qq * 128 + t;
    float ox = xp[3 * p], oy = xp[3 * p + 1], oz = xp[3 * p + 2];
    float oq = (ox * ox + oy * oy) + oz * oz;
    __syncthreads();

    float bmax = -1.0f, bmin = 3.0e38f;
    int   ima  = 0,     imi  = 0;
    #pragma unroll 8
    for (int m = 0; m < NPTS; ++m) {
        float4 qv = xyzS[m];                 // wave-uniform -> broadcast read
        float dt = (ox * qv.x + oy * qv.y) + oz * qv.z;   // == -2*dot, exact
        float d2 = (oq + qv.w) + dt;         // bits == ref d2 (pre-clamp)
        bool gt = d2 > bmax;                 // strict -> first occurrence
        ima = gt ? m : ima;  bmax = gt ? d2 : bmax;
        bool lt = (d2 < bmin) && (d2 > 0.0f);
        imi = lt ? m : imi;  bmin = lt ? d2 : bmin;
    }

    pmax[bl * NPTS + p] = ima;
    pmin[bl * NPTS + p] = imi;
}

// ---------------- K2: sim gathers (verbatim from the 115.8us round-0) ------
// Grid 2048 = 256 batches x 8 chunks of 16 ypred rows. Block 512 thr: thread
// t owns point n=t; reads a once, gathers both partners. ypred read exactly
// once from HBM chip-wide -> streaming-bound.
__global__ __launch_bounds__(512) void sim_kernel(
    const float* __restrict__ ypred,   // [NBATCH, JDIM, NPTS]
    const int* __restrict__ pmax,
    const int* __restrict__ pmin,
    float* __restrict__ partials)      // [2048]
{
    __shared__ float L[16 * NPTS];     // 32 KB tile
    __shared__ float wred[8];

    const int t  = threadIdx.x;
    const int bl = blockIdx.x >> 3;
    const int c  = blockIdx.x & 7;     // j-chunk

    // partner indices: issue early, land under the staging loads
    const int pma = pmax[bl * NPTS + t];
    const int pmi = pmin[bl * NPTS + t];

    const float4* src = (const float4*)(ypred + (size_t)bl * JDIM * NPTS
                                              + (size_t)c * 16 * NPTS);
    float4 v0 = src[t], v1 = src[512 + t], v2 = src[1024 + t], v3 = src[1536 + t];
    float4* dst = (float4*)L;
    dst[t] = v0;  dst[512 + t] = v1;  dst[1024 + t] = v2;  dst[1536 + t] = v3;
    __syncthreads();

    float accP = 0.0f, accM = 0.0f;
    #pragma unroll
    for (int r = 0; r < 16; ++r) {
        float a  = L[r * NPTS + t];      // stride-1, conflict-free
        float b  = L[r * NPTS + pma];    // random gather, ~2-way (free)
        float cm = L[r * NPTS + pmi];
        accP = fmaf(a, b, accP);
        accM = fmaf(a, cm, accM);
    }

    float d = accP - accM;
    #pragma unroll
    for (int off = 32; off > 0; off >>= 1)
        d += __shfl_down(d, off);
    if ((t & 63) == 0) wred[t >> 6] = d;
    __syncthreads();
    if (t == 0) {
        float ssum = 0.0f;
        #pragma unroll
        for (int w = 0; w < 8; ++w) ssum += wred[w];
        partials[blockIdx.x] = ssum;
    }
}

// ---------------- K3: final mean over 2048 partials (verbatim round-0) ------
__global__ __launch_bounds__(1024) void reduce_mean_kernel(
    const float* __restrict__ partials, float* __restrict__ out)
{
    const int t = threadIdx.x;
    float v = partials[t] + partials[t + 1024];
    #pragma unroll
    for (int off = 32; off > 0; off >>= 1)
        v += __shfl_down(v, off);

    __shared__ float w[16];
    if ((t & 63) == 0) w[t >> 6] = v;
    __syncthreads();
    if (t == 0) {
        float s = 0.0f;
        #pragma unroll
        for (int i = 0; i < 16; ++i) s += w[i];
        out[0] = s * (1.0f / (float)NPAIR);
    }
}

extern "C" void kernel_launch(void* const* d_in, const int* in_sizes, int n_in,
                              void* d_out, int out_size, void* d_ws, size_t ws_size,
                              hipStream_t stream) {
    const float* ypred = (const float*)d_in[0];   // [8,32,128,512] f32
    const float* xyz   = (const float*)d_in[1];   // [8,32,512,3]  f32

    // ws: pmax[131072] ints, pmin[131072] ints, partials[2048] floats (~1.06 MB)
    int*   pmax     = (int*)d_ws;
    int*   pmin     = pmax + NPAIR;
    float* partials = (float*)(pmin + NPAIR);
    float* out      = (float*)d_out;

    argmm_kernel<<<4 * NBATCH, 128, 0, stream>>>(xyz, pmax, pmin);
    sim_kernel<<<8 * NBATCH, 512, 0, stream>>>(ypred, pmax, pmin, partials);
    reduce_mean_kernel<<<1, 1024, 0, stream>>>(partials, out);
}

// Round 6
// 116.784 us; speedup vs baseline: 1.0735x; 1.0735x over previous
//
#include <hip/hip_runtime.h>

// Reference-exact fp32 d2: no FMA contraction. d2 = (sqn+sqm) + dot' with
// dot' built from (-2x) pre-scaled m-points is bit-identical to the ref's
// (sqn+sqm) - 2*dot (power-of-2 scaling / negation commute with rounding).
// Self-distance: dt(n,n) = -2*sq_n exactly, so d2(n,n) == 0 exactly.
#pragma clang fp contract(off)

#define NBATCH 256   // B*L
#define NPTS   512   // points per batch
#define JDIM   128   // logit dim
#define NPAIR  (NBATCH * NPTS)   // 131072

// ---------------- K1: 4 lanes/point, shfl-merged argmax / masked-argmin -----
// 1024 blocks x 512 threads (quarter-batch per block) -> 4 blocks/CU x 8
// waves = 32 waves/CU (FULL occupancy, the round-0 regime) with NO LDS merge:
// lanes 4g..4g+3 own point p, each scans one m-quarter ascending with strict
// compares, then a 2-stage __shfl_xor butterfly merges (strict compares keep
// the lower quarter on ties) == full ascending first-occurrence scan.
// LDS layout is quarter-skewed (+1 float4 per 128 points) so the 4 group
// addresses hit disjoint bank groups; the skew folds into a per-thread base
// pointer (zero per-iteration cost).
__global__ __launch_bounds__(512) void argmm_kernel(
    const float* __restrict__ xyz,   // [NBATCH, NPTS, 3]
    int* __restrict__ pmax,          // [NBATCH*NPTS]
    int* __restrict__ pmin)          // [NBATCH*NPTS]
{
    __shared__ float4 xyzS[NPTS + 4];        // skewed: phys = m + (m>>7)

    const int t  = threadIdx.x;              // 0..511
    const int bl = blockIdx.x >> 2;          // batch
    const int qq = blockIdx.x & 3;           // point-quarter of this block
    const float* xp = xyz + (size_t)bl * NPTS * 3;

    // stage all 512 points, scaled; sq computed in ref order from raw values
    {
        float x = xp[3 * t], y = xp[3 * t + 1], z = xp[3 * t + 2];
        float sq = (x * x + y * y) + z * z;  // matches np.sum(x*x,-1)
        xyzS[t + (t >> 7)] = make_float4(-2.0f * x, -2.0f * y, -2.0f * z, sq);
    }
    __syncthreads();

    const int p = qq * 128 + (t >> 2);       // point owned by this 4-lane group
    const int q = t & 3;                     // this lane's m-quarter

    // raw own coords recovered exactly: -0.5f * (-2x) == x (pow-2 scaling)
    float4 ov = xyzS[p + (p >> 7)];
    float ox = -0.5f * ov.x, oy = -0.5f * ov.y, oz = -0.5f * ov.z;
    float oq_ = ov.w;

    const float4* xb = &xyzS[q];             // +q == the quarter's skew
    const int m0 = q << 7;
    float bmax = -1.0f, bmin = 3.0e38f;
    int   ima  = m0,    imi  = m0;
    #pragma unroll 8
    for (int mm = 0; mm < 128; ++mm) {
        int m = m0 + mm;
        float4 qv = xb[m];                   // phys m+q == m+(m>>7) in-quarter
        float dt = (ox * qv.x + oy * qv.y) + oz * qv.z;   // == -2*dot, exact
        float d2 = (oq_ + qv.w) + dt;        // bits == ref d2 (pre-clamp)
        bool gt = d2 > bmax;                 // strict -> first occurrence
        ima = gt ? m : ima;  bmax = gt ? d2 : bmax;
        bool lt = (d2 < bmin) && (d2 > 0.0f);   // fold the d2==0 self/dupe mask
        imi = lt ? m : imi;  bmin = lt ? d2 : bmin;
    }

    // 2-stage butterfly over the aligned 4-lane group (in-wave, no barrier).
    // Quarters ascend with lane; strict compares keep the LOWER range on ties
    // at every stage -> global first-occurrence, matching the verified merge.
    #pragma unroll
    for (int st = 1; st <= 2; st <<= 1) {
        float obmax = __shfl_xor(bmax, st); int oima = __shfl_xor(ima, st);
        float obmin = __shfl_xor(bmin, st); int oimi = __shfl_xor(imi, st);
        bool hi = (t & st) != 0;             // my range is the upper of the pair
        float lmax = hi ? obmax : bmax;  int lima = hi ? oima : ima;
        float hmax = hi ? bmax : obmax;  int hima = hi ? ima  : oima;
        bool w = hmax > lmax;
        bmax = w ? hmax : lmax;  ima = w ? hima : lima;
        float lmin = hi ? obmin : bmin;  int limi = hi ? oimi : imi;
        float hmin = hi ? bmin : obmin;  int himi = hi ? imi  : oimi;
        bool x2 = hmin < lmin;
        bmin = x2 ? hmin : lmin;  imi = x2 ? himi : limi;
    }

    if (q == 0)      pmax[bl * NPTS + p] = ima;
    else if (q == 1) pmin[bl * NPTS + p] = imi;
}

// ---------------- K2: sim gathers (verbatim from the 115.8us round-0) ------
// Grid 2048 = 256 batches x 8 chunks of 16 ypred rows. Block 512 thr: thread
// t owns point n=t; reads a once, gathers both partners. ypred read exactly
// once from HBM chip-wide -> streaming-bound.
__global__ __launch_bounds__(512) void sim_kernel(
    const float* __restrict__ ypred,   // [NBATCH, JDIM, NPTS]
    const int* __restrict__ pmax,
    const int* __restrict__ pmin,
    float* __restrict__ partials)      // [2048]
{
    __shared__ float L[16 * NPTS];     // 32 KB tile
    __shared__ float wred[8];

    const int t  = threadIdx.x;
    const int bl = blockIdx.x >> 3;
    const int c  = blockIdx.x & 7;     // j-chunk

    // partner indices: issue early, land under the staging loads
    const int pma = pmax[bl * NPTS + t];
    const int pmi = pmin[bl * NPTS + t];

    const float4* src = (const float4*)(ypred + (size_t)bl * JDIM * NPTS
                                              + (size_t)c * 16 * NPTS);
    float4 v0 = src[t], v1 = src[512 + t], v2 = src[1024 + t], v3 = src[1536 + t];
    float4* dst = (float4*)L;
    dst[t] = v0;  dst[512 + t] = v1;  dst[1024 + t] = v2;  dst[1536 + t] = v3;
    __syncthreads();

    float accP = 0.0f, accM = 0.0f;
    #pragma unroll
    for (int r = 0; r < 16; ++r) {
        float a  = L[r * NPTS + t];      // stride-1, conflict-free
        float b  = L[r * NPTS + pma];    // random gather, ~2-way (free)
        float cm = L[r * NPTS + pmi];
        accP = fmaf(a, b, accP);
        accM = fmaf(a, cm, accM);
    }

    float d = accP - accM;
    #pragma unroll
    for (int off = 32; off > 0; off >>= 1)
        d += __shfl_down(d, off);
    if ((t & 63) == 0) wred[t >> 6] = d;
    __syncthreads();
    if (t == 0) {
        float ssum = 0.0f;
        #pragma unroll
        for (int w = 0; w < 8; ++w) ssum += wred[w];
        partials[blockIdx.x] = ssum;
    }
}

// ---------------- K3: final mean over 2048 partials (verbatim round-0) ------
__global__ __launch_bounds__(1024) void reduce_mean_kernel(
    const float* __restrict__ partials, float* __restrict__ out)
{
    const int t = threadIdx.x;
    float v = partials[t] + partials[t + 1024];
    #pragma unroll
    for (int off = 32; off > 0; off >>= 1)
        v += __shfl_down(v, off);

    __shared__ float w[16];
    if ((t & 63) == 0) w[t >> 6] = v;
    __syncthreads();
    if (t == 0) {
        float s = 0.0f;
        #pragma unroll
        for (int i = 0; i < 16; ++i) s += w[i];
        out[0] = s * (1.0f / (float)NPAIR);
    }
}

extern "C" void kernel_launch(void* const* d_in, const int* in_sizes, int n_in,
                              void* d_out, int out_size, void* d_ws, size_t ws_size,
                              hipStream_t stream) {
    const float* ypred = (const float*)d_in[0];   // [8,32,128,512] f32
    const float* xyz   = (const float*)d_in[1];   // [8,32,512,3]  f32

    // ws: pmax[131072] ints, pmin[131072] ints, partials[2048] floats (~1.06 MB)
    int*   pmax     = (int*)d_ws;
    int*   pmin     = pmax + NPAIR;
    float* partials = (float*)(pmin + NPAIR);
    float* out      = (float*)d_out;

    argmm_kernel<<<4 * NBATCH, 512, 0, stream>>>(xyz, pmax, pmin);
    sim_kernel<<<8 * NBATCH, 512, 0, stream>>>(ypred, pmax, pmin, partials);
    reduce_mean_kernel<<<1, 1024, 0, stream>>>(partials, out);
}